// Round 4
// baseline (473.975 us; speedup 1.0000x reference)
//
#include <hip/hip_runtime.h>

#define NEG_SLOPE 0.2f

typedef short bf16x8 __attribute__((ext_vector_type(8)));
typedef float f32x4 __attribute__((ext_vector_type(4)));

__device__ __forceinline__ float leaky1(float e) { return e > 0.f ? e : NEG_SLOPE * e; }

__device__ __forceinline__ unsigned short f2bf(float f) {
    unsigned u = __float_as_uint(f);
    u += 0x7fffu + ((u >> 16) & 1u);
    return (unsigned short)(u >> 16);
}

// split x into hi (bf16) + lo (bf16 of residual); hi+lo ~= x to ~2^-17 rel
__device__ __forceinline__ void split2(float x, short& h, short& lo) {
    unsigned short hb_ = f2bf(x);
    float hf = __uint_as_float(((unsigned)hb_) << 16);
    h = (short)hb_;
    lo = (short)f2bf(x - hf);
}

// ================= CSR build (bucketed, write-local) =================
// NOTE: packing requires N <= 2^17 (src fits 17 bits, local dst in bits 17..25).
#define EPB 4096   // edges per block in P1/P2 (391 blocks at E=1.6M)

// P1: per-bucket histogram (LDS) + per-block reserved base within each bucket.
__global__ __launch_bounds__(256) void bucket_hist(const int* __restrict__ dst,
                                                   int* __restrict__ gcnt,
                                                   int* __restrict__ relBase,
                                                   int E, int N, int NB) {
    __shared__ int hist[256];
    int t = threadIdx.x, blk = blockIdx.x;
    if (t < NB) hist[t] = 0;
    __syncthreads();
    int e0 = blk * EPB + t;
#pragma unroll 4
    for (int k = 0; k < EPB / 256; ++k) {
        int e = e0 + k * 256;
        if (e < E) {
            int d = dst[e];
            if ((unsigned)d < (unsigned)N) atomicAdd(&hist[d >> 9], 1);
        }
    }
    __syncthreads();
    if (t < NB) relBase[blk * NB + t] = atomicAdd(&gcnt[t], hist[t]);
}

// P2: scatter packed (src | local_dst<<17) into bucket-contiguous order.
// Self-scans gcnt (final after P1) to get bucket bases; no separate scan kernel.
__global__ __launch_bounds__(256) void bucket_scatter(const int* __restrict__ src,
                                                      const int* __restrict__ dst,
                                                      const int* __restrict__ gcnt,
                                                      const int* __restrict__ relBase,
                                                      int* __restrict__ eb,
                                                      int E, int N, int NB) {
    __shared__ int sm[256];
    __shared__ int cur[256];
    int t = threadIdx.x, blk = blockIdx.x;
    int v = (t < NB) ? gcnt[t] : 0;
    sm[t] = v;
    __syncthreads();
#pragma unroll
    for (int o = 1; o < 256; o <<= 1) {
        int u = (t >= o) ? sm[t - o] : 0;
        __syncthreads();
        sm[t] += u;
        __syncthreads();
    }
    if (t < NB) cur[t] = (sm[t] - v) + relBase[blk * NB + t];
    __syncthreads();
    int e0 = blk * EPB + t;
#pragma unroll 4
    for (int k = 0; k < EPB / 256; ++k) {
        int e = e0 + k * 256;
        if (e < E) {
            int d = dst[e];
            if ((unsigned)d < (unsigned)N) {
                int pos = atomicAdd(&cur[d >> 9], 1);
                eb[pos] = (src[e] & 0x1FFFF) | ((d & 511) << 17);
            }
        }
    }
}

// P3: one 512-thread block per bucket; self-scan gcnt for bucket ranges,
// local per-node count + LDS scan -> offs, then csr writes in a ~32KB window.
// Block NB-1 also writes offs[N] and the 16-entry zero pad of csr.
__global__ __launch_bounds__(512) void csr_build(const int* __restrict__ eb,
                                                 const int* __restrict__ gcnt,
                                                 int* __restrict__ offs,
                                                 int* __restrict__ csr,
                                                 int N, int NB) {
    __shared__ int gsm[512];
    __shared__ int lcnt[512];
    __shared__ int sm[512];
    __shared__ int cur[512];
    int t = threadIdx.x, b = blockIdx.x;
    int gv = (t < NB) ? gcnt[t] : 0;
    gsm[t] = gv;
    lcnt[t] = 0;
    __syncthreads();
#pragma unroll
    for (int o = 1; o < 512; o <<= 1) {
        int u = (t >= o) ? gsm[t - o] : 0;
        __syncthreads();
        gsm[t] += u;
        __syncthreads();
    }
    int s0 = (b == 0) ? 0 : gsm[b - 1];
    int s1 = gsm[b];
    int total = gsm[NB - 1];
    for (int e = s0 + t; e < s1; e += 512) atomicAdd(&lcnt[(eb[e] >> 17) & 511], 1);
    __syncthreads();
    int v = lcnt[t];
    sm[t] = v;
    __syncthreads();
#pragma unroll
    for (int o = 1; o < 512; o <<= 1) {
        int u = (t >= o) ? sm[t - o] : 0;
        __syncthreads();
        sm[t] += u;
        __syncthreads();
    }
    int base = s0 + sm[t] - v;   // exclusive within bucket
    cur[t] = base;
    int n0 = (b << 9) + t;
    if (n0 < N) offs[n0] = base;
    if (b == NB - 1) {
        if (t == 0) offs[N] = total;
        if (t < 16) csr[total + t] = 0;   // zero pad for agg tail reads
    }
    __syncthreads();
    for (int e = s0 + t; e < s1; e += 512) {
        int p = eb[e];
        int pos = atomicAdd(&cur[(p >> 17) & 511], 1);
        csr[pos] = p & 0x1FFFF;
    }
}

// ========== Dense GEMM via split-bf16 MFMA (fp32-accurate) ==========
// C = X(Mx128) @ W(128x128) as Ah*Bh + Ah*Bl + Al*Bh with mfma_16x16x32_bf16.
// 4 phases of K=32; LDS: A hi/lo [4][64][8] (8KB), B hi/lo [4][128][8] (16KB),
// optional Wr hi/lo (16KB) -> 40KB, 3 blocks/CU. Outputs: HB (bf16 h) +
// AoS scores sS4/sD4; optional R = X@Wr + rbias (residual, fused into gemm1).
// Epilogue transposes acc via f32 LDS [64][129] so thread (row, head q) owns
// 32 contiguous channels: in-thread score dots, coalesced stores.

__global__ __launch_bounds__(256, 3) void gemm_mfma(const float* __restrict__ X,
                                                    const float* __restrict__ W,
                                                    const float* __restrict__ Wr,
                                                    unsigned short* __restrict__ HB,
                                                    const float* __restrict__ rbias,
                                                    const float* __restrict__ ASrc,
                                                    const float* __restrict__ ADst,
                                                    float* __restrict__ sS4,
                                                    float* __restrict__ sD4,
                                                    float* __restrict__ R, int N) {
    __shared__ __align__(16) char pool[40960];
    short* Ah = (short*)pool;              // [4][64][8]   4 KB
    short* Al = (short*)(pool + 4096);
    short* Bh = (short*)(pool + 8192);     // [4][128][8]  8 KB
    short* Bl = (short*)(pool + 16384);
    short* Ch = (short*)(pool + 24576);    // Wr planes
    short* Cl = (short*)(pool + 32768);
    float* outS = (float*)pool;            // [64][129] f32 (33 KB, aliased)

    int t = threadIdx.x;
    int row0 = blockIdx.x << 6;
    int l = t & 63, w = t >> 6, g = l >> 4, r = l & 15;
    int r0 = w << 4;

    f32x4 acc[8], accR[8];
#pragma unroll
    for (int nb = 0; nb < 8; ++nb) {
        acc[nb] = (f32x4){0.f, 0.f, 0.f, 0.f};
        accR[nb] = (f32x4){0.f, 0.f, 0.f, 0.f};
    }

    int arow = t >> 2, akg = t & 3;
    int growA = row0 + arow;
    if (growA > N - 1) growA = N - 1;      // tail clamp (stores are guarded)
    int bc = t & 127, bk0 = (t >> 7) << 1;

#pragma unroll 1
    for (int ph = 0; ph < 4; ++ph) {
        __syncthreads();
        // ---- stage A: row arow, kgroup akg, k in [ph*32+akg*8, +8)
        {
            const float* xp = X + (size_t)growA * 128 + (ph << 5) + (akg << 3);
            float4 x0 = *(const float4*)(xp + 0);
            float4 x1 = *(const float4*)(xp + 4);
            float vv[8] = {x0.x, x0.y, x0.z, x0.w, x1.x, x1.y, x1.z, x1.w};
            bf16x8 hv, lv;
#pragma unroll
            for (int i = 0; i < 8; ++i) {
                short hh, ll;
                split2(vv[i], hh, ll);
                hv[i] = hh; lv[i] = ll;
            }
            *(bf16x8*)&Ah[(akg * 64 + arow) * 8] = hv;
            *(bf16x8*)&Al[(akg * 64 + arow) * 8] = lv;
        }
        // ---- stage B (and Wr): col bc, kgroups bk0, bk0+1
#pragma unroll
        for (int j = 0; j < 2; ++j) {
            int kg = bk0 + j;
            bf16x8 hv, lv;
#pragma unroll
            for (int i = 0; i < 8; ++i) {
                float f = W[(size_t)((ph << 5) + (kg << 3) + i) * 128 + bc];
                short hh, ll;
                split2(f, hh, ll);
                hv[i] = hh; lv[i] = ll;
            }
            *(bf16x8*)&Bh[(kg * 128 + bc) * 8] = hv;
            *(bf16x8*)&Bl[(kg * 128 + bc) * 8] = lv;
        }
        if (Wr) {
#pragma unroll
            for (int j = 0; j < 2; ++j) {
                int kg = bk0 + j;
                bf16x8 hv, lv;
#pragma unroll
                for (int i = 0; i < 8; ++i) {
                    float f = Wr[(size_t)((ph << 5) + (kg << 3) + i) * 128 + bc];
                    short hh, ll;
                    split2(f, hh, ll);
                    hv[i] = hh; lv[i] = ll;
                }
                *(bf16x8*)&Ch[(kg * 128 + bc) * 8] = hv;
                *(bf16x8*)&Cl[(kg * 128 + bc) * 8] = lv;
            }
        }
        __syncthreads();
        // ---- MFMA: K=32 per phase (kgroup g of 4)
        bf16x8 ah = *(const bf16x8*)&Ah[(g * 64 + r0 + r) * 8];
        bf16x8 al = *(const bf16x8*)&Al[(g * 64 + r0 + r) * 8];
#pragma unroll
        for (int nb = 0; nb < 8; ++nb) {
            bf16x8 bhv = *(const bf16x8*)&Bh[(g * 128 + (nb << 4) + r) * 8];
            bf16x8 blv = *(const bf16x8*)&Bl[(g * 128 + (nb << 4) + r) * 8];
            acc[nb] = __builtin_amdgcn_mfma_f32_16x16x32_bf16(ah, bhv, acc[nb], 0, 0, 0);
            acc[nb] = __builtin_amdgcn_mfma_f32_16x16x32_bf16(ah, blv, acc[nb], 0, 0, 0);
            acc[nb] = __builtin_amdgcn_mfma_f32_16x16x32_bf16(al, bhv, acc[nb], 0, 0, 0);
        }
        if (Wr) {
#pragma unroll
            for (int nb = 0; nb < 8; ++nb) {
                bf16x8 chv = *(const bf16x8*)&Ch[(g * 128 + (nb << 4) + r) * 8];
                bf16x8 clv = *(const bf16x8*)&Cl[(g * 128 + (nb << 4) + r) * 8];
                accR[nb] = __builtin_amdgcn_mfma_f32_16x16x32_bf16(ah, chv, accR[nb], 0, 0, 0);
                accR[nb] = __builtin_amdgcn_mfma_f32_16x16x32_bf16(ah, clv, accR[nb], 0, 0, 0);
                accR[nb] = __builtin_amdgcn_mfma_f32_16x16x32_bf16(al, chv, accR[nb], 0, 0, 0);
            }
        }
    }
    __syncthreads();
    // ---- main acc -> f32 LDS transpose (D map: col=lane&15, row=4*(lane>>4)+reg)
#pragma unroll
    for (int nb = 0; nb < 8; ++nb)
#pragma unroll
        for (int reg = 0; reg < 4; ++reg)
            outS[(r0 + (g << 2) + reg) * 129 + (nb << 4) + r] = acc[nb][reg];
    __syncthreads();
    int erow = t & 63, q = t >> 6;
    int grow = row0 + erow;
    float o[32];
#pragma unroll
    for (int i = 0; i < 32; ++i) o[i] = outS[erow * 129 + (q << 5) + i];
    if (grow < N) {
#pragma unroll
        for (int u = 0; u < 4; ++u) {
            uint4 hv;
            hv.x = (unsigned)f2bf(o[8 * u + 0]) | ((unsigned)f2bf(o[8 * u + 1]) << 16);
            hv.y = (unsigned)f2bf(o[8 * u + 2]) | ((unsigned)f2bf(o[8 * u + 3]) << 16);
            hv.z = (unsigned)f2bf(o[8 * u + 4]) | ((unsigned)f2bf(o[8 * u + 5]) << 16);
            hv.w = (unsigned)f2bf(o[8 * u + 6]) | ((unsigned)f2bf(o[8 * u + 7]) << 16);
            *(uint4*)(HB + (size_t)grow * 128 + (q << 5) + 8 * u) = hv;
        }
        if (ASrc) {
            float ps = 0.f, pd = 0.f;
#pragma unroll
            for (int i = 0; i < 32; ++i) {
                ps = fmaf(o[i], ASrc[(q << 5) + i], ps);
                pd = fmaf(o[i], ADst[(q << 5) + i], pd);
            }
            sS4[(size_t)grow * 4 + q] = ps;
            sD4[(size_t)grow * 4 + q] = pd;
        }
    }
    if (Wr) {
        __syncthreads();
#pragma unroll
        for (int nb = 0; nb < 8; ++nb)
#pragma unroll
            for (int reg = 0; reg < 4; ++reg)
                outS[(r0 + (g << 2) + reg) * 129 + (nb << 4) + r] = accR[nb][reg];
        __syncthreads();
        if (grow < N) {
#pragma unroll
            for (int i = 0; i < 8; ++i) {
                float4 v4;
                v4.x = outS[erow * 129 + (q << 5) + 4 * i + 0] + rbias[(q << 5) + 4 * i + 0];
                v4.y = outS[erow * 129 + (q << 5) + 4 * i + 1] + rbias[(q << 5) + 4 * i + 1];
                v4.z = outS[erow * 129 + (q << 5) + 4 * i + 2] + rbias[(q << 5) + 4 * i + 2];
                v4.w = outS[erow * 129 + (q << 5) + 4 * i + 3] + rbias[(q << 5) + 4 * i + 3];
                *(float4*)(R + (size_t)grow * 128 + (q << 5) + 4 * i) = v4;
            }
        }
    }
}

// ============ fused softmax-weight + gather-accumulate (v7 + resid) ============
// One wave per dst node, 16 lanes per edge (16B = 8 channels per lane),
// 4 edges in flight per wave-iteration. q=lane>>4 picks edge base+4i+q;
// cl=lane&15 owns channels 8cl..8cl+7 (head hd=cl>>2). Weight per lane:
//   w = exp(leaky(sS4[sj*4+hd] + sdh))   (broadcast 16B line, L2-hot)
// csr zero-padded by 16 -> no tail clamp; tail weights forced to 0.
// Epilogue combines quarters via shfl_xor(16/32); optional resid add (layer 2:
// resid = x@Wr + br, precomputed in gemm1's fused dispatch).

__global__ __launch_bounds__(256) void agg7_kernel(const unsigned short* __restrict__ hb,
                                                   const float* __restrict__ sS4,
                                                   const float* __restrict__ sD4,
                                                   const int* __restrict__ offs,
                                                   const int* __restrict__ csr,
                                                   const float* __restrict__ bias,
                                                   const float* __restrict__ resid,
                                                   float* __restrict__ out,
                                                   int do_relu, int N) {
    int n = (blockIdx.x << 2) + (threadIdx.x >> 6);
    if (n >= N) return;
    int lane = threadIdx.x & 63;
    int q    = lane >> 4;               // quarter: which of 4 concurrent edges
    int cl   = lane & 15;               // channel group: channels 8cl..8cl+7
    int hd   = cl >> 2;                 // head
    unsigned clo = (unsigned)cl << 4;   // byte offset of this lane's 16B

    float sdh = sD4[(n << 2) + hd];     // dst-score, loop-invariant per lane
    float selfw = __expf(leaky1(sS4[(n << 2) + hd] + sdh));

    float acc[8] = {0.f, 0.f, 0.f, 0.f, 0.f, 0.f, 0.f, 0.f};
    float wsum = 0.f;

    int off = offs[n], end = offs[n + 1];
#pragma unroll 1
    for (int base = off; base < end; base += 16) {
        int e0 = base + q;
        int sj[4];
        float wj[4];
#pragma unroll
        for (int i = 0; i < 4; ++i) sj[i] = csr[e0 + (i << 2)];   // pad-safe
#pragma unroll
        for (int i = 0; i < 4; ++i) {
            float s = sS4[((unsigned)sj[i] << 2) + hd] + sdh;
            float w = __expf(leaky1(s));
            wj[i] = (e0 + (i << 2) < end) ? w : 0.f;
        }
#pragma unroll
        for (int i = 0; i < 4; ++i) {
            uint4 v = *(const uint4*)((const char*)hb + (((unsigned)sj[i] << 8) + clo));
            float w = wj[i];
            wsum += w;
            acc[0] = fmaf(w, __uint_as_float(v.x << 16), acc[0]);
            acc[1] = fmaf(w, __uint_as_float(v.x & 0xffff0000u), acc[1]);
            acc[2] = fmaf(w, __uint_as_float(v.y << 16), acc[2]);
            acc[3] = fmaf(w, __uint_as_float(v.y & 0xffff0000u), acc[3]);
            acc[4] = fmaf(w, __uint_as_float(v.z << 16), acc[4]);
            acc[5] = fmaf(w, __uint_as_float(v.z & 0xffff0000u), acc[5]);
            acc[6] = fmaf(w, __uint_as_float(v.w << 16), acc[6]);
            acc[7] = fmaf(w, __uint_as_float(v.w & 0xffff0000u), acc[7]);
        }
    }
    // combine the 4 quarters (disjoint edge subsets)
#pragma unroll
    for (int k = 0; k < 8; ++k) {
        acc[k] += __shfl_xor(acc[k], 16);
        acc[k] += __shfl_xor(acc[k], 32);
    }
    wsum += __shfl_xor(wsum, 16);
    wsum += __shfl_xor(wsum, 32);

    float iv = 1.0f / (wsum + selfw);

    if (q == 0) {
        uint4 hv = *(const uint4*)((const char*)hb + (((unsigned)n << 8) + clo));
        float hs[8];
        hs[0] = __uint_as_float(hv.x << 16);
        hs[1] = __uint_as_float(hv.x & 0xffff0000u);
        hs[2] = __uint_as_float(hv.y << 16);
        hs[3] = __uint_as_float(hv.y & 0xffff0000u);
        hs[4] = __uint_as_float(hv.z << 16);
        hs[5] = __uint_as_float(hv.z & 0xffff0000u);
        hs[6] = __uint_as_float(hv.w << 16);
        hs[7] = __uint_as_float(hv.w & 0xffff0000u);
        float4 b0 = *(const float4*)&bias[8 * cl];
        float4 b1 = *(const float4*)&bias[8 * cl + 4];
        float4 o0, o1;
        o0.x = fmaf(fmaf(selfw, hs[0], acc[0]), iv, b0.x);
        o0.y = fmaf(fmaf(selfw, hs[1], acc[1]), iv, b0.y);
        o0.z = fmaf(fmaf(selfw, hs[2], acc[2]), iv, b0.z);
        o0.w = fmaf(fmaf(selfw, hs[3], acc[3]), iv, b0.w);
        o1.x = fmaf(fmaf(selfw, hs[4], acc[4]), iv, b1.x);
        o1.y = fmaf(fmaf(selfw, hs[5], acc[5]), iv, b1.y);
        o1.z = fmaf(fmaf(selfw, hs[6], acc[6]), iv, b1.z);
        o1.w = fmaf(fmaf(selfw, hs[7], acc[7]), iv, b1.w);
        if (resid) {
            float4 r0v = *(const float4*)(resid + (size_t)n * 128 + 8 * cl);
            float4 r1v = *(const float4*)(resid + (size_t)n * 128 + 8 * cl + 4);
            o0.x += r0v.x; o0.y += r0v.y; o0.z += r0v.z; o0.w += r0v.w;
            o1.x += r1v.x; o1.y += r1v.y; o1.z += r1v.z; o1.w += r1v.w;
        }
        if (do_relu) {
            o0.x = fmaxf(o0.x, 0.f); o0.y = fmaxf(o0.y, 0.f);
            o0.z = fmaxf(o0.z, 0.f); o0.w = fmaxf(o0.w, 0.f);
            o1.x = fmaxf(o1.x, 0.f); o1.y = fmaxf(o1.y, 0.f);
            o1.z = fmaxf(o1.z, 0.f); o1.w = fmaxf(o1.w, 0.f);
        }
        *(float4*)(out + (size_t)n * 128 + 8 * cl) = o0;
        *(float4*)(out + (size_t)n * 128 + 8 * cl + 4) = o1;
    }
}

// ================= host =================

extern "C" void kernel_launch(void* const* d_in, const int* in_sizes, int n_in,
                              void* d_out, int out_size, void* d_ws, size_t ws_size,
                              hipStream_t stream) {
    const float* x   = (const float*)d_in[0];
    const int*   ei  = (const int*)d_in[1];
    const float* W1  = (const float*)d_in[2];
    const float* a1s = (const float*)d_in[3];
    const float* a1d = (const float*)d_in[4];
    const float* b1  = (const float*)d_in[5];
    const float* W2  = (const float*)d_in[6];
    const float* a2s = (const float*)d_in[7];
    const float* a2d = (const float*)d_in[8];
    const float* b2  = (const float*)d_in[9];
    const float* Wr  = (const float*)d_in[10];
    const float* br  = (const float*)d_in[11];
    float* out = (float*)d_out;

    int N = in_sizes[0] / 128;
    int E = in_sizes[1] / 2;
    const int* src = ei;
    const int* dst = ei + E;
    int NB = (N + 511) >> 9;               // 196 buckets of 512 nodes
    int ebl = (E + EPB - 1) / EPB;         // 391 blocks in P1/P2

    char* w = (char*)d_ws;
    size_t p = 0;
    auto take = [&](size_t bytes) -> char* {
        char* r = w + p;
        p = (p + bytes + 255) & ~(size_t)255;
        return r;
    };
    float* bufB = (float*)take((size_t)N * 128 * 4);                  // h1 fp32
    float* Rbuf = (float*)take((size_t)N * 128 * 4);                  // x@Wr + br
    unsigned short* hb = (unsigned short*)take((size_t)N * 128 * 2);  // h bf16
    float* sS4  = (float*)take((size_t)N * 4 * 4);                    // AoS [node][4]
    float* sD4  = (float*)take((size_t)N * 4 * 4);
    int* gcnt   = (int*)take((size_t)256 * 4);
    int* offs   = (int*)take((size_t)(N + 1) * 4);
    int* relBase = (int*)take((size_t)ebl * NB * 4);
    int* eb     = (int*)take((size_t)E * 4);                          // packed
    int* csr    = (int*)take((size_t)(E + 16) * 4);                   // +16 pad

    hipMemsetAsync(gcnt, 0, 256 * 4, stream);

    bucket_hist<<<ebl, 256, 0, stream>>>(dst, gcnt, relBase, E, N, NB);
    bucket_scatter<<<ebl, 256, 0, stream>>>(src, dst, gcnt, relBase, eb, E, N, NB);
    csr_build<<<NB, 512, 0, stream>>>(eb, gcnt, offs, csr, N, NB);

    int gbm = (N + 63) >> 6;
    int ab = (N + 3) / 4;

    // layer 1 + fused residual: hb1/scores + R = x@Wr + br
    gemm_mfma<<<gbm, 256, 0, stream>>>(x, W1, Wr, hb, br, a1s, a1d, sS4, sD4, Rbuf, N);
    agg7_kernel<<<ab, 256, 0, stream>>>(hb, sS4, sD4, offs, csr, b1, nullptr, bufB, 1, N);
    // layer 2
    gemm_mfma<<<gbm, 256, 0, stream>>>(bufB, W2, nullptr, hb, nullptr, a2s, a2d, sS4, sD4, nullptr, N);
    agg7_kernel<<<ab, 256, 0, stream>>>(hb, sS4, sD4, offs, csr, b2, Rbuf, out, 0, N);
}

// Round 5
// 419.293 us; speedup vs baseline: 1.1304x; 1.1304x over previous
//
#include <hip/hip_runtime.h>

#define NEG_SLOPE 0.2f

typedef short bf16x8 __attribute__((ext_vector_type(8)));
typedef float f32x4 __attribute__((ext_vector_type(4)));

__device__ __forceinline__ float leaky1(float e) { return e > 0.f ? e : NEG_SLOPE * e; }

__device__ __forceinline__ unsigned short f2bf(float f) {
    unsigned u = __float_as_uint(f);
    u += 0x7fffu + ((u >> 16) & 1u);
    return (unsigned short)(u >> 16);
}

// split x into hi (bf16) + lo (bf16 of residual); hi+lo ~= x to ~2^-17 rel
__device__ __forceinline__ void split2(float x, short& h, short& lo) {
    unsigned short hb_ = f2bf(x);
    float hf = __uint_as_float(((unsigned)hb_) << 16);
    h = (short)hb_;
    lo = (short)f2bf(x - hf);
}

// ================= CSR build (bucketed, write-local) =================
// NOTE: packing requires N <= 2^17 (src fits 17 bits, local dst in bits 17..25).
#define EPB 4096   // edges per block in P1/P2 (391 blocks at E=1.6M)

// P1: per-bucket histogram (LDS) + per-block reserved base within each bucket.
__global__ __launch_bounds__(256) void bucket_hist(const int* __restrict__ dst,
                                                   int* __restrict__ gcnt,
                                                   int* __restrict__ relBase,
                                                   int E, int N, int NB) {
    __shared__ int hist[256];
    int t = threadIdx.x, blk = blockIdx.x;
    if (t < NB) hist[t] = 0;
    __syncthreads();
    int e0 = blk * EPB + t;
#pragma unroll 4
    for (int k = 0; k < EPB / 256; ++k) {
        int e = e0 + k * 256;
        if (e < E) {
            int d = dst[e];
            if ((unsigned)d < (unsigned)N) atomicAdd(&hist[d >> 9], 1);
        }
    }
    __syncthreads();
    if (t < NB) relBase[blk * NB + t] = atomicAdd(&gcnt[t], hist[t]);
}

// P2: scatter packed (src | local_dst<<17) into bucket-contiguous order.
// Self-scans gcnt (final after P1) to get bucket bases; no separate scan kernel.
__global__ __launch_bounds__(256) void bucket_scatter(const int* __restrict__ src,
                                                      const int* __restrict__ dst,
                                                      const int* __restrict__ gcnt,
                                                      const int* __restrict__ relBase,
                                                      int* __restrict__ eb,
                                                      int E, int N, int NB) {
    __shared__ int sm[256];
    __shared__ int cur[256];
    int t = threadIdx.x, blk = blockIdx.x;
    int v = (t < NB) ? gcnt[t] : 0;
    sm[t] = v;
    __syncthreads();
#pragma unroll
    for (int o = 1; o < 256; o <<= 1) {
        int u = (t >= o) ? sm[t - o] : 0;
        __syncthreads();
        sm[t] += u;
        __syncthreads();
    }
    if (t < NB) cur[t] = (sm[t] - v) + relBase[blk * NB + t];
    __syncthreads();
    int e0 = blk * EPB + t;
#pragma unroll 4
    for (int k = 0; k < EPB / 256; ++k) {
        int e = e0 + k * 256;
        if (e < E) {
            int d = dst[e];
            if ((unsigned)d < (unsigned)N) {
                int pos = atomicAdd(&cur[d >> 9], 1);
                eb[pos] = (src[e] & 0x1FFFF) | ((d & 511) << 17);
            }
        }
    }
}

// P3: one 512-thread block per bucket; self-scan gcnt for bucket ranges,
// local per-node count + LDS scan -> offs, then csr writes in a ~32KB window.
// Block NB-1 also writes offs[N] and the 16-entry zero pad of csr.
__global__ __launch_bounds__(512) void csr_build(const int* __restrict__ eb,
                                                 const int* __restrict__ gcnt,
                                                 int* __restrict__ offs,
                                                 int* __restrict__ csr,
                                                 int N, int NB) {
    __shared__ int gsm[512];
    __shared__ int lcnt[512];
    __shared__ int sm[512];
    __shared__ int cur[512];
    int t = threadIdx.x, b = blockIdx.x;
    int gv = (t < NB) ? gcnt[t] : 0;
    gsm[t] = gv;
    lcnt[t] = 0;
    __syncthreads();
#pragma unroll
    for (int o = 1; o < 512; o <<= 1) {
        int u = (t >= o) ? gsm[t - o] : 0;
        __syncthreads();
        gsm[t] += u;
        __syncthreads();
    }
    int s0 = (b == 0) ? 0 : gsm[b - 1];
    int s1 = gsm[b];
    int total = gsm[NB - 1];
    for (int e = s0 + t; e < s1; e += 512) atomicAdd(&lcnt[(eb[e] >> 17) & 511], 1);
    __syncthreads();
    int v = lcnt[t];
    sm[t] = v;
    __syncthreads();
#pragma unroll
    for (int o = 1; o < 512; o <<= 1) {
        int u = (t >= o) ? sm[t - o] : 0;
        __syncthreads();
        sm[t] += u;
        __syncthreads();
    }
    int base = s0 + sm[t] - v;   // exclusive within bucket
    cur[t] = base;
    int n0 = (b << 9) + t;
    if (n0 < N) offs[n0] = base;
    if (b == NB - 1) {
        if (t == 0) offs[N] = total;
        if (t < 16) csr[total + t] = 0;   // zero pad for agg tail reads
    }
    __syncthreads();
    for (int e = s0 + t; e < s1; e += 512) {
        int p = eb[e];
        int pos = atomicAdd(&cur[(p >> 17) & 511], 1);
        csr[pos] = p & 0x1FFFF;
    }
}

// ========== Dense GEMM via split-bf16 MFMA (fp32-accurate) ==========
// C = X(MxK=128) * W(K=128 x N=128), computed as Ah*Bh + Ah*Bl + Al*Bh with
// mfma_f32_16x16x32_bf16 (error ~2^-17 rel, same as fp32 chain).
// Block: 64 rows, 4 waves, wave w owns rows 16w..16w+15, all 128 cols.
// 2 phases of K=64. LDS: k-major tiles At2[h/l][8][64][8], Bt2[h/l][8][128][8]
// bf16 (conflict-free b128). Epilogue: acc -> f32 LDS [64][129] transpose;
// thread (row, quarter q) owns cols 32q..32q+31 = head q, so the attention
// score dots are in-thread (no shuffles), HB/OUT stores coalesced.
// Layer GEMMs: OUT=null, HB=bf16 h, scores AoS sS4/sD4. Residual: OUT=out,
// accumulate, bias=br.

__global__ __launch_bounds__(256, 3) void gemm_mfma(const float* __restrict__ X,
                                                    const float* __restrict__ W,
                                                    float* __restrict__ OUT,
                                                    unsigned short* __restrict__ HB,
                                                    const float* __restrict__ bias,
                                                    int accumulate,
                                                    const float* __restrict__ ASrc,
                                                    const float* __restrict__ ADst,
                                                    float* __restrict__ sS4,
                                                    float* __restrict__ sD4, int N) {
    __shared__ __align__(16) char pool[49152];
    short* At2h = (short*)pool;              // [8][64][8]  8 KB
    short* At2l = (short*)(pool + 8192);     // [8][64][8]  8 KB
    short* Bt2h = (short*)(pool + 16384);    // [8][128][8] 16 KB
    short* Bt2l = (short*)(pool + 32768);    // [8][128][8] 16 KB
    float* outS = (float*)pool;              // [64][129] f32 (33 KB, aliased)

    int t = threadIdx.x;
    int row0 = blockIdx.x << 6;
    int l = t & 63, w = t >> 6, g = l >> 4, r = l & 15;
    int r0 = w << 4;

    f32x4 acc[8];
#pragma unroll
    for (int nb = 0; nb < 8; ++nb) acc[nb] = (f32x4){0.f, 0.f, 0.f, 0.f};

    int arow = t >> 2, aj = t & 3;
    int growA = row0 + arow;
    if (growA > N - 1) growA = N - 1;        // tail clamp (stores are guarded)
    int bc = t & 127, bh4 = (t >> 7) << 2;

#pragma unroll 1
    for (int ph = 0; ph < 2; ++ph) {
        __syncthreads();
        // ---- stage A: this thread covers k in [ph*64+16aj, +16) of row arow
        {
            const float* xp = X + (size_t)growA * 128 + (ph << 6) + (aj << 4);
            float4 x0 = *(const float4*)(xp + 0);
            float4 x1 = *(const float4*)(xp + 4);
            float4 x2 = *(const float4*)(xp + 8);
            float4 x3 = *(const float4*)(xp + 12);
            float v[16] = {x0.x, x0.y, x0.z, x0.w, x1.x, x1.y, x1.z, x1.w,
                           x2.x, x2.y, x2.z, x2.w, x3.x, x3.y, x3.z, x3.w};
#pragma unroll
            for (int u = 0; u < 2; ++u) {
                bf16x8 hv, lv;
#pragma unroll
                for (int i = 0; i < 8; ++i) {
                    short hh, ll;
                    split2(v[u * 8 + i], hh, ll);
                    hv[i] = hh; lv[i] = ll;
                }
                int kg = 2 * aj + u;
                *(bf16x8*)&At2h[(kg * 64 + arow) * 8] = hv;
                *(bf16x8*)&At2l[(kg * 64 + arow) * 8] = lv;
            }
        }
        // ---- stage B: this thread covers col bc, k-groups bh4..bh4+3
        {
#pragma unroll
            for (int j = 0; j < 4; ++j) {
                int kg = bh4 + j;
                bf16x8 hv, lv;
#pragma unroll
                for (int i = 0; i < 8; ++i) {
                    float f = W[(size_t)((ph << 6) + (kg << 3) + i) * 128 + bc];
                    short hh, ll;
                    split2(f, hh, ll);
                    hv[i] = hh; lv[i] = ll;
                }
                *(bf16x8*)&Bt2h[(kg * 128 + bc) * 8] = hv;
                *(bf16x8*)&Bt2l[(kg * 128 + bc) * 8] = lv;
            }
        }
        __syncthreads();
        // ---- MFMA: 2 k-chunks of 32 per phase
#pragma unroll
        for (int m = 0; m < 2; ++m) {
            int kb = m << 2;
            bf16x8 ah = *(const bf16x8*)&At2h[((kb + g) * 64 + r0 + r) * 8];
            bf16x8 al = *(const bf16x8*)&At2l[((kb + g) * 64 + r0 + r) * 8];
#pragma unroll
            for (int nb = 0; nb < 8; ++nb) {
                bf16x8 bhv = *(const bf16x8*)&Bt2h[((kb + g) * 128 + (nb << 4) + r) * 8];
                bf16x8 blv = *(const bf16x8*)&Bt2l[((kb + g) * 128 + (nb << 4) + r) * 8];
                acc[nb] = __builtin_amdgcn_mfma_f32_16x16x32_bf16(ah, bhv, acc[nb], 0, 0, 0);
                acc[nb] = __builtin_amdgcn_mfma_f32_16x16x32_bf16(ah, blv, acc[nb], 0, 0, 0);
                acc[nb] = __builtin_amdgcn_mfma_f32_16x16x32_bf16(al, bhv, acc[nb], 0, 0, 0);
            }
        }
    }
    __syncthreads();
    // ---- acc -> f32 LDS transpose (D map: col = lane&15, row = 4*(lane>>4)+reg)
#pragma unroll
    for (int nb = 0; nb < 8; ++nb)
#pragma unroll
        for (int reg = 0; reg < 4; ++reg)
            outS[(r0 + (g << 2) + reg) * 129 + (nb << 4) + r] = acc[nb][reg];
    __syncthreads();
    // ---- epilogue: thread owns (row = t&63, quarter q = t>>6) = head q
    int erow = t & 63, q = t >> 6;
    int grow = row0 + erow;
    if (grow < N) {
        float o[32];
#pragma unroll
        for (int i = 0; i < 32; ++i) o[i] = outS[erow * 129 + (q << 5) + i];
        if (bias) {
#pragma unroll
            for (int i = 0; i < 32; ++i) o[i] += bias[(q << 5) + i];
        }
        if (accumulate) {
#pragma unroll
            for (int i = 0; i < 8; ++i) {
                float4 old = *(const float4*)(OUT + (size_t)grow * 128 + (q << 5) + 4 * i);
                o[4 * i] += old.x; o[4 * i + 1] += old.y;
                o[4 * i + 2] += old.z; o[4 * i + 3] += old.w;
            }
        }
        if (OUT) {
#pragma unroll
            for (int i = 0; i < 8; ++i) {
                float4 v4 = make_float4(o[4 * i], o[4 * i + 1], o[4 * i + 2], o[4 * i + 3]);
                *(float4*)(OUT + (size_t)grow * 128 + (q << 5) + 4 * i) = v4;
            }
        }
        if (HB) {
#pragma unroll
            for (int u = 0; u < 4; ++u) {
                uint4 hv;
                hv.x = (unsigned)f2bf(o[8 * u + 0]) | ((unsigned)f2bf(o[8 * u + 1]) << 16);
                hv.y = (unsigned)f2bf(o[8 * u + 2]) | ((unsigned)f2bf(o[8 * u + 3]) << 16);
                hv.z = (unsigned)f2bf(o[8 * u + 4]) | ((unsigned)f2bf(o[8 * u + 5]) << 16);
                hv.w = (unsigned)f2bf(o[8 * u + 6]) | ((unsigned)f2bf(o[8 * u + 7]) << 16);
                *(uint4*)(HB + (size_t)grow * 128 + (q << 5) + 8 * u) = hv;
            }
        }
        if (ASrc) {
            float ps = 0.f, pd = 0.f;
#pragma unroll
            for (int i = 0; i < 32; ++i) {
                ps = fmaf(o[i], ASrc[(q << 5) + i], ps);
                pd = fmaf(o[i], ADst[(q << 5) + i], pd);
            }
            sS4[(size_t)grow * 4 + q] = ps;
            sD4[(size_t)grow * 4 + q] = pd;
        }
    }
}

// ============ fused softmax-weight + gather-accumulate (v7) ============
// One wave per dst node, 16 lanes per edge (16B = 8 channels per lane),
// 4 edges in flight per wave-iteration. q=lane>>4 picks edge base+4i+q;
// cl=lane&15 owns channels 8cl..8cl+7 (head hd=cl>>2). Weight per lane:
//   w = exp(leaky(sS4[sj*4+hd] + sdh))   (broadcast 16B line, L2-hot)
// csr is zero-padded by 16 so no tail clamp; tail weights forced to 0
// (row-0 gathers are L1-hot, harmless). Epilogue: shfl_xor(16/32) combines
// the 4 quarters' disjoint edge subsets for acc[8] and wsum.
// No max-subtraction: |scores| small, exp safe, softmax shift-invariant.

__global__ __launch_bounds__(256) void agg7_kernel(const unsigned short* __restrict__ hb,
                                                   const float* __restrict__ sS4,
                                                   const float* __restrict__ sD4,
                                                   const int* __restrict__ offs,
                                                   const int* __restrict__ csr,
                                                   const float* __restrict__ bias,
                                                   float* __restrict__ out,
                                                   int do_relu, int N) {
    int n = (blockIdx.x << 2) + (threadIdx.x >> 6);
    if (n >= N) return;
    int lane = threadIdx.x & 63;
    int q    = lane >> 4;               // quarter: which of 4 concurrent edges
    int cl   = lane & 15;               // channel group: channels 8cl..8cl+7
    int hd   = cl >> 2;                 // head
    unsigned clo = (unsigned)cl << 4;   // byte offset of this lane's 16B

    float sdh = sD4[(n << 2) + hd];     // dst-score, loop-invariant per lane
    float selfw = __expf(leaky1(sS4[(n << 2) + hd] + sdh));

    float acc[8] = {0.f, 0.f, 0.f, 0.f, 0.f, 0.f, 0.f, 0.f};
    float wsum = 0.f;

    int off = offs[n], end = offs[n + 1];
#pragma unroll 1
    for (int base = off; base < end; base += 16) {
        int e0 = base + q;
        int sj[4];
        float wj[4];
#pragma unroll
        for (int i = 0; i < 4; ++i) sj[i] = csr[e0 + (i << 2)];   // pad-safe
#pragma unroll
        for (int i = 0; i < 4; ++i) {
            float s = sS4[((unsigned)sj[i] << 2) + hd] + sdh;
            float w = __expf(leaky1(s));
            wj[i] = (e0 + (i << 2) < end) ? w : 0.f;
        }
#pragma unroll
        for (int i = 0; i < 4; ++i) {
            uint4 v = *(const uint4*)((const char*)hb + (((unsigned)sj[i] << 8) + clo));
            float w = wj[i];
            wsum += w;
            acc[0] = fmaf(w, __uint_as_float(v.x << 16), acc[0]);
            acc[1] = fmaf(w, __uint_as_float(v.x & 0xffff0000u), acc[1]);
            acc[2] = fmaf(w, __uint_as_float(v.y << 16), acc[2]);
            acc[3] = fmaf(w, __uint_as_float(v.y & 0xffff0000u), acc[3]);
            acc[4] = fmaf(w, __uint_as_float(v.z << 16), acc[4]);
            acc[5] = fmaf(w, __uint_as_float(v.z & 0xffff0000u), acc[5]);
            acc[6] = fmaf(w, __uint_as_float(v.w << 16), acc[6]);
            acc[7] = fmaf(w, __uint_as_float(v.w & 0xffff0000u), acc[7]);
        }
    }
    // combine the 4 quarters (disjoint edge subsets)
#pragma unroll
    for (int k = 0; k < 8; ++k) {
        acc[k] += __shfl_xor(acc[k], 16);
        acc[k] += __shfl_xor(acc[k], 32);
    }
    wsum += __shfl_xor(wsum, 16);
    wsum += __shfl_xor(wsum, 32);

    float iv = 1.0f / (wsum + selfw);

    if (q == 0) {
        uint4 hv = *(const uint4*)((const char*)hb + (((unsigned)n << 8) + clo));
        float hs[8];
        hs[0] = __uint_as_float(hv.x << 16);
        hs[1] = __uint_as_float(hv.x & 0xffff0000u);
        hs[2] = __uint_as_float(hv.y << 16);
        hs[3] = __uint_as_float(hv.y & 0xffff0000u);
        hs[4] = __uint_as_float(hv.z << 16);
        hs[5] = __uint_as_float(hv.z & 0xffff0000u);
        hs[6] = __uint_as_float(hv.w << 16);
        hs[7] = __uint_as_float(hv.w & 0xffff0000u);
        float4 b0 = *(const float4*)&bias[8 * cl];
        float4 b1 = *(const float4*)&bias[8 * cl + 4];
        float4 o0, o1;
        o0.x = fmaf(fmaf(selfw, hs[0], acc[0]), iv, b0.x);
        o0.y = fmaf(fmaf(selfw, hs[1], acc[1]), iv, b0.y);
        o0.z = fmaf(fmaf(selfw, hs[2], acc[2]), iv, b0.z);
        o0.w = fmaf(fmaf(selfw, hs[3], acc[3]), iv, b0.w);
        o1.x = fmaf(fmaf(selfw, hs[4], acc[4]), iv, b1.x);
        o1.y = fmaf(fmaf(selfw, hs[5], acc[5]), iv, b1.y);
        o1.z = fmaf(fmaf(selfw, hs[6], acc[6]), iv, b1.z);
        o1.w = fmaf(fmaf(selfw, hs[7], acc[7]), iv, b1.w);
        if (do_relu) {
            o0.x = fmaxf(o0.x, 0.f); o0.y = fmaxf(o0.y, 0.f);
            o0.z = fmaxf(o0.z, 0.f); o0.w = fmaxf(o0.w, 0.f);
            o1.x = fmaxf(o1.x, 0.f); o1.y = fmaxf(o1.y, 0.f);
            o1.z = fmaxf(o1.z, 0.f); o1.w = fmaxf(o1.w, 0.f);
        }
        *(float4*)(out + (size_t)n * 128 + 8 * cl) = o0;
        *(float4*)(out + (size_t)n * 128 + 8 * cl + 4) = o1;
    }
}

// ================= host =================

extern "C" void kernel_launch(void* const* d_in, const int* in_sizes, int n_in,
                              void* d_out, int out_size, void* d_ws, size_t ws_size,
                              hipStream_t stream) {
    const float* x   = (const float*)d_in[0];
    const int*   ei  = (const int*)d_in[1];
    const float* W1  = (const float*)d_in[2];
    const float* a1s = (const float*)d_in[3];
    const float* a1d = (const float*)d_in[4];
    const float* b1  = (const float*)d_in[5];
    const float* W2  = (const float*)d_in[6];
    const float* a2s = (const float*)d_in[7];
    const float* a2d = (const float*)d_in[8];
    const float* b2  = (const float*)d_in[9];
    const float* Wr  = (const float*)d_in[10];
    const float* br  = (const float*)d_in[11];
    float* out = (float*)d_out;

    int N = in_sizes[0] / 128;
    int E = in_sizes[1] / 2;
    const int* src = ei;
    const int* dst = ei + E;
    int NB = (N + 511) >> 9;               // 196 buckets of 512 nodes
    int ebl = (E + EPB - 1) / EPB;         // 391 blocks in P1/P2

    char* w = (char*)d_ws;
    size_t p = 0;
    auto take = [&](size_t bytes) -> char* {
        char* r = w + p;
        p = (p + bytes + 255) & ~(size_t)255;
        return r;
    };
    float* bufB = (float*)take((size_t)N * 128 * 4);                  // h1 fp32
    unsigned short* hb = (unsigned short*)take((size_t)N * 128 * 2);  // h bf16
    float* sS4  = (float*)take((size_t)N * 4 * 4);                    // AoS [node][4]
    float* sD4  = (float*)take((size_t)N * 4 * 4);
    int* gcnt   = (int*)take((size_t)256 * 4);
    int* offs   = (int*)take((size_t)(N + 1) * 4);
    int* relBase = (int*)take((size_t)ebl * NB * 4);
    int* eb     = (int*)take((size_t)E * 4);                          // packed
    int* csr    = (int*)take((size_t)(E + 16) * 4);                   // +16 pad

    hipMemsetAsync(gcnt, 0, 256 * 4, stream);

    bucket_hist<<<ebl, 256, 0, stream>>>(dst, gcnt, relBase, E, N, NB);
    bucket_scatter<<<ebl, 256, 0, stream>>>(src, dst, gcnt, relBase, eb, E, N, NB);
    csr_build<<<NB, 512, 0, stream>>>(eb, gcnt, offs, csr, N, NB);

    int gbm = (N + 63) >> 6;
    int ab = (N + 3) / 4;

    // layer 1: gemm emits bf16 h + AoS scores only (no fp32 h)
    gemm_mfma<<<gbm, 256, 0, stream>>>(x, W1, nullptr, hb, nullptr, 0, a1s, a1d, sS4, sD4, N);
    agg7_kernel<<<ab, 256, 0, stream>>>(hb, sS4, sD4, offs, csr, b1, bufB, 1, N);
    // layer 2
    gemm_mfma<<<gbm, 256, 0, stream>>>(bufB, W2, nullptr, hb, nullptr, 0, a2s, a2d, sS4, sD4, N);
    agg7_kernel<<<ab, 256, 0, stream>>>(hb, sS4, sD4, offs, csr, b2, out, 0, N);
    // residual: out += x @ Wr + br
    gemm_mfma<<<gbm, 256, 0, stream>>>(x, Wr, out, nullptr, br, 1, nullptr, nullptr, nullptr, nullptr, N);
}